// Round 16
// baseline (240.125 us; speedup 1.0000x reference)
//
#include <hip/hip_runtime.h>
#include <math.h>

#define Bb 64
#define Qn 512
#define Kn 512
#define Cn 256
#define Hn 8
#define HDn 32
#define OUTn 256

typedef __bf16 bf16_t;
typedef _Float16 fp16_t;
typedef __attribute__((ext_vector_type(4))) __bf16 bf16x4;
typedef __attribute__((ext_vector_type(8))) __bf16 bf16x8;
typedef __attribute__((ext_vector_type(4))) _Float16 h16x4;
typedef __attribute__((ext_vector_type(8))) _Float16 h16x8;
typedef __attribute__((ext_vector_type(4))) float f32x4;
typedef __attribute__((ext_vector_type(4))) unsigned int u32x4;

__device__ inline bf16_t tob(float f) {
    unsigned int u = __float_as_uint(f);
    u += 0x7fff + ((u >> 16) & 1);   // RNE
    unsigned short s = (unsigned short)(u >> 16);
    return __builtin_bit_cast(bf16_t, s);
}

// async global->LDS, 16B per lane; LDS dest = wave-uniform base + lane*16
__device__ inline void gl_lds16(const void* g, void* l) {
    __builtin_amdgcn_global_load_lds(
        (const __attribute__((address_space(1))) unsigned int*)g,
        (__attribute__((address_space(3))) unsigned int*)l, 16, 0, 0);
}

// ---------------- weight prep: cast to bf16, MFMA-fragment-tiled ----------
// weights stored in the exact B-fragment order proj/outproj consume:
//   element (n, k) -> wt[ ((n>>4)*8 + (k>>5))*512 + lane*8 + (k&7) ],
//   lane = ((k>>3)&3)*16 + (n&15).
__global__ __launch_bounds__(256) void prep_weights(
    const float* __restrict__ qw, const float* __restrict__ kw,
    const float* __restrict__ vw, const float* __restrict__ gw,
    const float* __restrict__ ow,
    bf16_t* __restrict__ wtq, bf16_t* __restrict__ wtk,
    bf16_t* __restrict__ wtv, bf16_t* __restrict__ wtg,
    bf16_t* __restrict__ wto)
{
    int tid = blockIdx.x * 256 + threadIdx.x;   // 0 .. 5*65536-1
    int mat = tid >> 16;
    int rem = tid & 65535;
    int a = rem >> 8;    // source row (k dim)
    int n = rem & 255;   // source col (n dim)
    const float* src = mat == 0 ? qw : mat == 1 ? kw : mat == 2 ? vw : mat == 3 ? gw : ow;
    bf16_t* dst = mat == 0 ? wtq : mat == 1 ? wtk : mat == 2 ? wtv : mat == 3 ? wtg : wto;
    int nb = n >> 4, kb = a >> 5, rg = (a >> 3) & 3, e = a & 7, nl = n & 15;
    size_t idx = (((size_t)(nb * 8 + kb) * 64) + rg * 16 + nl) * 8 + e;
    dst[idx] = tob(src[a * 256 + n]);
}

// ---------------- fused projections + bias tiling (R14/R15/R16) -----------
// R16: FAT-WAVE proj. Exoneration ledger: stores coalesced (R9 -5%),
// weight loads coalesced (R10 -11%), MORE occupancy falsified (R11:
// 23->44% = zero gain, +31MB FETCH). Direction signal: R10 64x64/wave
// beat R11 32x64/wave -> per-wave ILP is the axis. This round: 256-thd
// blocks (4 waves), SAME 1024-block grid and SAME per-block 64x256 X tile
// (FETCH unchanged -- the R11 confound removed); each wave owns 64x128:
// acc[4][8], 2x MFMA + 2x outstanding loads per wave, half the
// barrier/epilogue events per CU. ~200 VGPR -> ~8 waves/CU = proj's
// measured achieved occupancy anyway (occupancy lever already falsified).
// prep part re-indexed for 256 thd; 4:9 interleave (R14) kept; fp16 bias
// tiles (R15) kept.
#define ALDS_STRIDE 264   // 256 + 8 pad
__global__ __launch_bounds__(256) void proj_prep_kernel(
    const float* __restrict__ qdata, const float* __restrict__ mdata,
    const bf16_t* __restrict__ wtq, const bf16_t* __restrict__ wtk,
    const bf16_t* __restrict__ wtv, const bf16_t* __restrict__ wtg,
    const float* __restrict__ gating_b,
    bf16_t* __restrict__ qb, bf16_t* __restrict__ kb,
    bf16_t* __restrict__ vTb, bf16_t* __restrict__ gateb,
    const float* __restrict__ bias, const float* __restrict__ nbias,
    float* __restrict__ btile, float* __restrict__ ntile)
{
    __shared__ __align__(16) char smem_raw[33792];   // A-tile 33792 / prep 33024
    const int bid = blockIdx.x;
    const int grp = bid / 13;
    const int rem = bid % 13;
    const int tid = threadIdx.x;

    if (rem >= 4) {
        // ---------------- prep_bias tile (LDS transpose -> fp16 out) ------
        float* tl = (float*)smem_raw;     // 16 x 516 f32 = 33024B
        const int pid = grp * 9 + (rem - 4);      // 0..2303
        const bool isn = pid >= 2048;
        const int id2 = isn ? pid - 2048 : pid;   // (b or h)*32 + q16
        const int q16 = id2 & 31;
        const int bh = id2 >> 5;
        const float* src = (isn ? nbias : bias) + ((size_t)bh * Qn + q16 * 16) * Kn;
        fp16_t* dst = (fp16_t*)(isn ? ntile : btile) + ((size_t)id2 << 13);
        const float L = 1.4426950408889634f;

        #pragma unroll
        for (int i = 0; i < 8; i++) {
            int u = tid + i * 256;        // 2048 f32x4 units
            int row = u >> 7;             // 0..15
            int c4 = u & 127;             // col/4
            f32x4 v = *reinterpret_cast<const f32x4*>(src + (size_t)row * Kn + c4 * 4);
            *reinterpret_cast<f32x4*>(&tl[row * 516 + c4 * 4]) = v;
        }
        __syncthreads();
        #pragma unroll
        for (int i = 0; i < 8; i++) {
            int u = tid + i * 256;        // (c, lane, t), t fastest
            int t = u & 3;
            int lane = (u >> 2) & 63;
            int c = u >> 8;
            int row = lane & 15;
            int col = c * 64 + t * 16 + ((lane >> 4) << 2);
            f32x4 v = *reinterpret_cast<const f32x4*>(&tl[row * 516 + col]);
            h16x4 hv;
            #pragma unroll
            for (int k = 0; k < 4; k++) hv[k] = (fp16_t)(v[k] * L);
            *reinterpret_cast<h16x4*>(dst + c * 1024 + lane * 16 + t * 4) = hv;
        }
        return;
    }

    // -------------------- proj: 4 waves, 64 rows x 128 cols per wave ------
    bf16_t* smem = (bf16_t*)smem_raw;
    bf16_t* alds = smem;
    const int id = grp * 4 + rem;         // 0..1023
    const int side = id >> 9;             // 0: q_data, 1: m_data
    const int m0 = (id & 511) * 64;
    const int lane = tid & 63;
    const int w = tid >> 6;               // wave 0..3
    const int ch = w >> 1;                // 0: q|k, 1: gate|v
    const int ncb = (w & 1) * 128;        // wave's 128-col base
    const int c15 = lane & 15;
    const int rgrp = lane >> 4;
    const int kof = rgrp * 8;
    const float* X = side ? mdata : qdata;
    const bf16_t* Wt = side == 0 ? (ch == 0 ? wtq : wtg) : (ch == 0 ? wtk : wtv);
    const bool vout = (side == 1) && (ch == 1);

    // ---- stage A: 64 rows x 256 f32 -> bf16 LDS (cvt_pk + b64 writes) ----
    #pragma unroll
    for (int i = 0; i < 16; i++) {
        int u = tid + i * 256;            // 4096 f32x4 units
        int row = u >> 6;
        int c4 = u & 63;
        f32x4 a4 = *reinterpret_cast<const f32x4*>(X + (size_t)(m0 + row) * 256 + c4 * 4);
        unsigned int p0, p1;
        asm("v_cvt_pk_bf16_f32 %0, %1, %2" : "=v"(p0) : "v"(a4[0]), "v"(a4[1]));
        asm("v_cvt_pk_bf16_f32 %0, %1, %2" : "=v"(p1) : "v"(a4[2]), "v"(a4[3]));
        unsigned long long pk = ((unsigned long long)p1 << 32) | p0;
        *reinterpret_cast<unsigned long long*>(&alds[row * ALDS_STRIDE + c4 * 4]) = pk;
    }
    __syncthreads();

    const bf16_t* wbase = Wt + (size_t)(ncb >> 4) * 8 * 512 + lane * 8;
    f32x4 acc[4][8] = {};
    #pragma unroll 1
    for (int kc = 0; kc < 8; kc++) {
        bf16x8 am[4], bn[8];
        #pragma unroll
        for (int i = 0; i < 4; i++)
            am[i] = *reinterpret_cast<const bf16x8*>(&alds[(i * 16 + c15) * ALDS_STRIDE + kc * 32 + kof]);
        #pragma unroll
        for (int j = 0; j < 8; j++)
            bn[j] = *reinterpret_cast<const bf16x8*>(wbase + ((size_t)j * 8 + kc) * 512);
        #pragma unroll
        for (int i = 0; i < 4; i++)
            #pragma unroll
            for (int j = 0; j < 8; j++) {
                if (vout)
                    acc[i][j] = __builtin_amdgcn_mfma_f32_16x16x32_bf16(bn[j], am[i], acc[i][j], 0, 0, 0);
                else
                    acc[i][j] = __builtin_amdgcn_mfma_f32_16x16x32_bf16(am[i], bn[j], acc[i][j], 0, 0, 0);
            }
    }

    __syncthreads();                      // A-tile reads done; reuse as scratch
    bf16_t* scr = smem + w * 2560;        // per-wave slice (5120B), 16B-aligned

    // q is pre-scaled by log2(e)/sqrt(32): softmax computes exp2 directly.
    const float scale = 0.17677669529663687f * 1.4426950408889634f;
    const int posbase = m0 & 511;
    const int b = m0 >> 9;

    if (!vout) {
        bf16_t* dst = side == 0 ? (ch == 0 ? qb : gateb) : kb;
        #pragma unroll
        for (int jh = 0; jh < 2; jh++) {          // column halves (64 each)
            const int hbase = (ncb + jh * 64) >> 5;
            #pragma unroll
            for (int P = 0; P < 2; P++) {         // row halves (32 each)
                // stage 32 rows x 64 cols -> scr[row][col], stride 72
                #pragma unroll
                for (int ii = 0; ii < 2; ii++) {
                    int i = P * 2 + ii;
                    #pragma unroll
                    for (int jl = 0; jl < 4; jl++) {
                        int j = jh * 4 + jl;
                        int n = ncb + j * 16 + c15;
                        #pragma unroll
                        for (int r = 0; r < 4; r++) {
                            float v = acc[i][j][r];
                            if (side == 0) {
                                if (ch == 0) v *= scale;
                                else v = 1.f / (1.f + __expf(-(v + gating_b[n])));
                            }
                            scr[(ii * 16 + rgrp * 4 + r) * 72 + jl * 16 + c15] = tob(v);
                        }
                    }
                }
                asm volatile("" ::: "memory");
                // coalesced write-out: 4 iters x 16B/lane, full 64B lines
                #pragma unroll
                for (int v2 = 0; v2 < 4; v2++) {
                    int row = v2 * 8 + (lane >> 3);
                    int col = (lane & 7) * 8;
                    bf16x8 val = *reinterpret_cast<const bf16x8*>(&scr[row * 72 + col]);
                    int pos = posbase + P * 32 + row;
                    int hh = hbase + (col >> 5);
                    int d = col & 31;
                    *reinterpret_cast<bf16x8*>(dst + (((size_t)(b * Hn + hh) * Qn + pos) << 5) + d) = val;
                }
                asm volatile("" ::: "memory");
            }
        }
    } else {
        // transposed acc: lanes index m-rows (key positions), regs index n
        // kk perm folded into the LDS WRITE column; readback stride-1 in kk.
        #pragma unroll
        for (int jh = 0; jh < 2; jh++) {          // column halves (64 n each)
            const int hbase = (ncb + jh * 64) >> 5;
            #pragma unroll
            for (int P = 0; P < 2; P++) {         // pos halves (32 each)
                #pragma unroll
                for (int ii = 0; ii < 2; ii++) {
                    int i = P * 2 + ii;
                    int kperm = (((c15 >> 3) & 1) << 4) | (((c15 >> 2) & 1) << 3) | (ii << 2)
                              | (((c15 >> 1) & 1) << 1) | (c15 & 1);
                    #pragma unroll
                    for (int jl = 0; jl < 4; jl++) {
                        int j = jh * 4 + jl;
                        #pragma unroll
                        for (int r = 0; r < 4; r++)
                            scr[(jl * 16 + rgrp * 4 + r) * 40 + kperm] = tob(acc[i][j][r]);
                    }
                }
                asm volatile("" ::: "memory");
                #pragma unroll
                for (int u = 0; u < 4; u++) {
                    int nloc = u * 16 + (lane >> 2);
                    int koff = (lane & 3) * 8;
                    bf16x8 val = *reinterpret_cast<const bf16x8*>(&scr[nloc * 40 + koff]);
                    int hh = hbase + (nloc >> 5);
                    int d = nloc & 31;
                    *reinterpret_cast<bf16x8*>(vTb + ((size_t)(b * Hn + hh) * HDn + d) * Kn
                                               + posbase + P * 32 + koff) = val;
                }
                asm volatile("" ::: "memory");
            }
        }
    }
}

// ---------------- fused attention, FP16-TILED-BIAS (R15, unchanged) -------
// bias/nbias pre-tiled fp16 (pre-scaled by log2e) -> per chunk, 4 coalesced
// 16B loads. LDS = 16KB kv dbuf only. Counted vmcnt(4): at the wait,
// outstanding = stage(c)[2 oldest] + bias(c)[4 newer].
__global__ __launch_bounds__(256) void attn_kernel(
    const bf16_t* __restrict__ qb, const bf16_t* __restrict__ kb,
    const bf16_t* __restrict__ vTb, const bf16_t* __restrict__ gateb,
    const float* __restrict__ btile, const float* __restrict__ ntile,
    bf16_t* __restrict__ wab)
{
    __shared__ __align__(16) char kvlds[2][8192];    // [buf][K 4KB | V 4KB]
    const int p = blockIdx.x;
    const int qt = p & 7;
    const int h = (p >> 3) & 7;
    const int b = p >> 6;
    const int lane = threadIdx.x & 63;
    const int wv = threadIdx.x >> 6;
    const int q0 = qt * 64 + wv * 16;
    const int q16 = qt * 4 + wv;
    const int c15 = lane & 15;
    const int rgrp = lane >> 4;
    const int kof = rgrp * 8;

    const bf16_t* qbase = qb + (size_t)(b * Hn + h) * Qn * HDn;
    const bf16_t* kbase = kb + (size_t)(b * Hn + h) * Kn * HDn;
    const bf16_t* vbase = vTb + (size_t)(b * Hn + h) * HDn * Kn;
    const fp16_t* btb = (const fp16_t*)btile + (((size_t)b * 32 + q16) << 13) + lane * 16;
    const fp16_t* ntb = (const fp16_t*)ntile + (((size_t)h * 32 + q16) << 13) + lane * 16;

    // staging lane geometry (constant per thread)
    const int krw = (wv << 4) + (lane >> 2);        // K row 0..63
    const int kcb = (lane & 3) << 4;                // K col byte
    const int vrw = (wv << 3) + (lane >> 3);        // V row 0..31
    const int vcb = (lane & 7) << 4;                // V col byte
    const size_t ksrc0 = ((size_t)krw << 6) + (size_t)(kcb ^ ((krw & 3) << 4));
    const size_t vsrc0 = ((size_t)vrw << 10) + (size_t)(vcb ^ ((vrw & 7) << 4));

    bf16x8 aq = *reinterpret_cast<const bf16x8*>(qbase + (q0 + c15) * HDn + kof);

    const float NML = -12.f * 1.4426950408889634f;   // -M*log2e, folded into QK^T C
    const f32x4 zML = {NML, NML, NML, NML};
    f32x4 o[2] = {};
    f32x4 lsv = {0.f, 0.f, 0.f, 0.f};

    // ---- prologue: stage chunk 0 -> LDS buf 0 ----
    gl_lds16((const char*)kbase + ksrc0, (char*)kvlds[0] + wv * 1024);
    gl_lds16((const char*)vbase + vsrc0, (char*)kvlds[0] + 4096 + wv * 1024);

    #pragma unroll 1
    for (int c = 0; c < 8; c++) {         // 8 chunks of 64 k-cols
        const int pb = c & 1;
        // ---- bias/nbias fp16 tiled loads: 4 coalesced 16B (newest VMEM) ----
        h16x8 bt0 = *reinterpret_cast<const h16x8*>(btb + c * 1024);
        h16x8 bt1 = *reinterpret_cast<const h16x8*>(btb + c * 1024 + 8);
        h16x8 nt0 = *reinterpret_cast<const h16x8*>(ntb + c * 1024);
        h16x8 nt1 = *reinterpret_cast<const h16x8*>(ntb + c * 1024 + 8);
        // ---- counted drain: kill stage(c) [2 oldest], keep bias [4] ----
        __builtin_amdgcn_sched_barrier(0);
        asm volatile("s_waitcnt vmcnt(4)" ::: "memory");
        __builtin_amdgcn_s_barrier();
        __builtin_amdgcn_sched_barrier(0);
        // ---- issue stage(c+1) into the other buffer (safe: post-barrier) --
        if (c < 7) {
            char* dstb = (char*)kvlds[pb ^ 1] + wv * 1024;
            gl_lds16((const char*)kbase + (size_t)((c + 1) << 12) + ksrc0, dstb);
            gl_lds16((const char*)vbase + (size_t)((c + 1) << 7) + vsrc0, dstb + 4096);
        }
        // ---- QK^T from LDS K tile (swizzled read) ----
        const char* kl = (const char*)kvlds[pb];
        f32x4 sc[4];
        #pragma unroll
        for (int t = 0; t < 4; t++) {
            int kr = t * 16 + c15;
            bf16x8 kf = *reinterpret_cast<const bf16x8*>(kl + (kr << 6) + ((rgrp << 4) ^ ((kr & 3) << 4)));
            sc[t] = __builtin_amdgcn_mfma_f32_16x16x32_bf16(kf, aq, zML, 0, 0, 0);
        }
        // ---- softmax: e = exp2(sc + bb); bb from fp16 tiles; cvt_pk P ----
        f32x4 es[4];
        #pragma unroll
        for (int t = 0; t < 4; t++) {
            #pragma unroll
            for (int r = 0; r < 4; r++) {
                int j = (t & 1) * 4 + r;
                float bbv = (t < 2)
                    ? ((float)bt0[j] + (float)nt0[j])
                    : ((float)bt1[j] + (float)nt1[j]);
                es[t][r] = __builtin_amdgcn_exp2f(sc[t][r] + bbv);
            }
            lsv += es[t];
        }
        unsigned int pw[8];
        #pragma unroll
        for (int t = 0; t < 4; t++) {
            asm("v_cvt_pk_bf16_f32 %0, %1, %2" : "=v"(pw[t * 2 + 0]) : "v"(es[t][0]), "v"(es[t][1]));
            asm("v_cvt_pk_bf16_f32 %0, %1, %2" : "=v"(pw[t * 2 + 1]) : "v"(es[t][2]), "v"(es[t][3]));
        }
        u32x4 a0 = {pw[0], pw[1], pw[2], pw[3]};
        u32x4 a1 = {pw[4], pw[5], pw[6], pw[7]};
        bf16x8 pa0 = __builtin_bit_cast(bf16x8, a0);
        bf16x8 pa1 = __builtin_bit_cast(bf16x8, a1);
        // ---- PV from LDS V tile (swizzled read), P in-register ----
        #pragma unroll
        for (int sub = 0; sub < 2; sub++) {
            bf16x8 ap = sub == 0 ? pa0 : pa1;
            #pragma unroll
            for (int nt = 0; nt < 2; nt++) {
                int vr = nt * 16 + c15;
                bf16x8 bv = *reinterpret_cast<const bf16x8*>(kl + 4096 + (vr << 7)
                                + (((sub << 6) | (rgrp << 4)) ^ ((vr & 7) << 4)));
                o[nt] = __builtin_amdgcn_mfma_f32_16x16x32_bf16(ap, bv, o[nt], 0, 0, 0);
            }
        }
    }

    float lsum = (lsv[0] + lsv[1]) + (lsv[2] + lsv[3]);
    lsum += __shfl_xor(lsum, 16, 64);
    lsum += __shfl_xor(lsum, 32, 64);
    float linv[4];
    #pragma unroll
    for (int r = 0; r < 4; r++)
        linv[r] = 1.f / __shfl(lsum, rgrp * 4 + r, 64);

    // epilogue: normalize, gate, store wa as bf16 [B,Q,H*HD]
    const bf16_t* gptr = gateb + (size_t)(b * Hn + h) * Qn * HDn;
    bf16_t* wptr = wab + (size_t)b * Qn * 256;
    const int qg = q0 + rgrp * 4;
    #pragma unroll
    for (int nt = 0; nt < 2; nt++) {
        int d = nt * 16 + c15;
        #pragma unroll
        for (int r = 0; r < 4; r++) {
            float g = (float)gptr[(qg + r) * HDn + d];
            wptr[(qg + r) * 256 + h * 32 + d] = tob(o[nt][r] * linv[r] * g);
        }
    }
}

// ---------------- output projection + bias ----------------
__global__ __launch_bounds__(256) void outproj_kernel(
    const bf16_t* __restrict__ wab, const bf16_t* __restrict__ wto,
    const float* __restrict__ outb, float* __restrict__ out)
{
    __shared__ bf16_t alds[64 * ALDS_STRIDE];
    const int m0 = blockIdx.x * 64;
    const int tid = threadIdx.x;
    const int lane = tid & 63;
    const int w = tid >> 6;
    const int ncb = w * 64;
    const int c15 = lane & 15;
    const int rgrp = lane >> 4;
    const int kof = rgrp * 8;

    #pragma unroll
    for (int i = 0; i < 8; i++) {
        int u = tid + i * 256;
        int row = u >> 5;
        int c16 = u & 31;
        bf16x8 a8 = *reinterpret_cast<const bf16x8*>(wab + (size_t)(m0 + row) * 256 + c16 * 8);
        *reinterpret_cast<bf16x8*>(&alds[row * ALDS_STRIDE + c16 * 8]) = a8;
    }
    __syncthreads();

    const bf16_t* wbase = wto + (size_t)(ncb >> 4) * 8 * 512 + lane * 8;
    f32x4 acc[4][4] = {};
    #pragma unroll
    for (int kc = 0; kc < 8; kc++) {
        bf16x8 am[4], bn[4];
        #pragma unroll
        for (int i = 0; i < 4; i++)
            am[i] = *reinterpret_cast<const bf16x8*>(&alds[(i * 16 + c15) * ALDS_STRIDE + kc * 32 + kof]);
        #pragma unroll
        for (int j = 0; j < 4; j++)
            bn[j] = *reinterpret_cast<const bf16x8*>(wbase + ((size_t)j * 8 + kc) * 512);
        #pragma unroll
        for (int i = 0; i < 4; i++)
            #pragma unroll
            for (int j = 0; j < 4; j++)
                acc[i][j] = __builtin_amdgcn_mfma_f32_16x16x32_bf16(am[i], bn[j], acc[i][j], 0, 0, 0);
    }

    #pragma unroll
    for (int j = 0; j < 4; j++) {
        int n = ncb + j * 16 + c15;
        float ob = outb[n];
        #pragma unroll
        for (int i = 0; i < 4; i++) {
            #pragma unroll
            for (int r = 0; r < 4; r++) {
                int m = m0 + i * 16 + rgrp * 4 + r;
                out[(size_t)m * 256 + n] = acc[i][j][r] + ob;
            }
        }
    }
}

extern "C" void kernel_launch(void* const* d_in, const int* in_sizes, int n_in,
                              void* d_out, int out_size, void* d_ws, size_t ws_size,
                              hipStream_t stream) {
    const float* q_data = (const float*)d_in[0];
    const float* m_data = (const float*)d_in[1];
    const float* bias = (const float*)d_in[2];
    const float* nbias = (const float*)d_in[3];
    const float* query_w = (const float*)d_in[4];
    const float* key_w = (const float*)d_in[5];
    const float* value_w = (const float*)d_in[6];
    const float* gating_w = (const float*)d_in[7];
    const float* gating_b = (const float*)d_in[8];
    const float* output_w = (const float*)d_in[9];
    const float* output_b = (const float*)d_in[10];
    float* out = (float*)d_out;

    char* ws = (char*)d_ws;
    const size_t WT = 256 * 256 * sizeof(bf16_t);
    const size_t PROJ = (size_t)Bb * Hn * Qn * HDn;      // bf16 elems
    bf16_t* wtq = (bf16_t*)(ws);
    bf16_t* wtk = (bf16_t*)(ws + WT);
    bf16_t* wtv = (bf16_t*)(ws + 2 * WT);
    bf16_t* wtg = (bf16_t*)(ws + 3 * WT);
    bf16_t* wto = (bf16_t*)(ws + 4 * WT);
    bf16_t* qb = (bf16_t*)(ws + 5 * WT);
    bf16_t* kb = qb + PROJ;
    bf16_t* vtb = kb + PROJ;
    bf16_t* gateb = vtb + PROJ;
    bf16_t* wab = gateb + PROJ;

    const size_t BASE = 5 * WT + 5 * PROJ * sizeof(bf16_t);
    const size_t BT_BYTES = (size_t)64 * 32 * 8192 * 2;  // fp16 tiles, 33.5 MB
    float* btile = (float*)(ws + BASE);
    float* ntile = (float*)(ws + BASE + BT_BYTES);

    prep_weights<<<1280, 256, 0, stream>>>(query_w, key_w, value_w, gating_w, output_w,
                                           wtq, wtk, wtv, wtg, wto);
    proj_prep_kernel<<<3328, 256, 0, stream>>>(q_data, m_data, wtq, wtk, wtv, wtg,
                                               gating_b, qb, kb, vtb, gateb,
                                               bias, nbias, btile, ntile);
    attn_kernel<<<4096, 256, 0, stream>>>(qb, kb, vtb, gateb, btile, ntile, wab);
    outproj_kernel<<<512, 256, 0, stream>>>(wab, wto, output_b, out);
}

// Round 17
// 148.007 us; speedup vs baseline: 1.6224x; 1.6224x over previous
//
#include <hip/hip_runtime.h>
#include <math.h>

#define Bb 64
#define Qn 512
#define Kn 512
#define Cn 256
#define Hn 8
#define HDn 32
#define OUTn 256

typedef __bf16 bf16_t;
typedef _Float16 fp16_t;
typedef __attribute__((ext_vector_type(4))) __bf16 bf16x4;
typedef __attribute__((ext_vector_type(8))) __bf16 bf16x8;
typedef __attribute__((ext_vector_type(4))) _Float16 h16x4;
typedef __attribute__((ext_vector_type(8))) _Float16 h16x8;
typedef __attribute__((ext_vector_type(4))) float f32x4;
typedef __attribute__((ext_vector_type(4))) unsigned int u32x4;

__device__ inline bf16_t tob(float f) {
    unsigned int u = __float_as_uint(f);
    u += 0x7fff + ((u >> 16) & 1);   // RNE
    unsigned short s = (unsigned short)(u >> 16);
    return __builtin_bit_cast(bf16_t, s);
}

// async global->LDS, 16B per lane; LDS dest = wave-uniform base + lane*16
__device__ inline void gl_lds16(const void* g, void* l) {
    __builtin_amdgcn_global_load_lds(
        (const __attribute__((address_space(1))) unsigned int*)g,
        (__attribute__((address_space(3))) unsigned int*)l, 16, 0, 0);
}

// ---------------- weight prep: cast to bf16, MFMA-fragment-tiled ----------
// weights stored in the exact B-fragment order proj/outproj consume:
//   element (n, k) -> wt[ ((n>>4)*8 + (k>>5))*512 + lane*8 + (k&7) ],
//   lane = ((k>>3)&3)*16 + (n&15).
__global__ __launch_bounds__(256) void prep_weights(
    const float* __restrict__ qw, const float* __restrict__ kw,
    const float* __restrict__ vw, const float* __restrict__ gw,
    const float* __restrict__ ow,
    bf16_t* __restrict__ wtq, bf16_t* __restrict__ wtk,
    bf16_t* __restrict__ wtv, bf16_t* __restrict__ wtg,
    bf16_t* __restrict__ wto)
{
    int tid = blockIdx.x * 256 + threadIdx.x;   // 0 .. 5*65536-1
    int mat = tid >> 16;
    int rem = tid & 65535;
    int a = rem >> 8;    // source row (k dim)
    int n = rem & 255;   // source col (n dim)
    const float* src = mat == 0 ? qw : mat == 1 ? kw : mat == 2 ? vw : mat == 3 ? gw : ow;
    bf16_t* dst = mat == 0 ? wtq : mat == 1 ? wtk : mat == 2 ? wtv : mat == 3 ? wtg : wto;
    int nb = n >> 4, kb = a >> 5, rg = (a >> 3) & 3, e = a & 7, nl = n & 15;
    size_t idx = (((size_t)(nb * 8 + kb) * 64) + rg * 16 + nl) * 8 + e;
    dst[idx] = tob(src[a * 256 + n]);
}

// ---------------- fused projections + bias tiling (R13/R14/R15) -----------
// R14 interleave: rem=bid%13: rem<4 -> proj (4:9 ratio, bijective), else
// prep. Every 13 consecutive IDs = 4 proj + 9 prep -> CU-level overlap;
// fused incremental prep cost ~= prep's HBM-BW floor (overlap maxed).
// R15: bias tiles stored as FP16 pre-scaled by log2e (attn was
// bias-L2-BW-bound at ~35 TB/s ~= the L2 ceiling; fp16 halves the stream).
// R16 NOTE (falsified): fat-wave proj (acc[4][8]) spills (VGPR 136,
// occupancy 9.5%, 2.2x slower). With R11 (more occupancy = 0 gain) both
// ends of the occupancy<->ILP axis are closed; this R10-form proj is the
// measured optimum.
// Tile layout (per (b|h, q16), 8192 fp16 = 16KB):
//   tile[c 8][lane 64][j 16], j = t*4+r,
//   value = LOG2E * bias[bh][q16*16+(lane&15)][c*64+t*16+(lane>>4)*4+r]
#define ALDS_STRIDE 264   // 256 + 8 pad
__global__ __launch_bounds__(512) void proj_prep_kernel(
    const float* __restrict__ qdata, const float* __restrict__ mdata,
    const bf16_t* __restrict__ wtq, const bf16_t* __restrict__ wtk,
    const bf16_t* __restrict__ wtv, const bf16_t* __restrict__ wtg,
    const float* __restrict__ gating_b,
    bf16_t* __restrict__ qb, bf16_t* __restrict__ kb,
    bf16_t* __restrict__ vTb, bf16_t* __restrict__ gateb,
    const float* __restrict__ bias, const float* __restrict__ nbias,
    float* __restrict__ btile, float* __restrict__ ntile)
{
    __shared__ __align__(16) char smem_raw[40960];
    const int bid = blockIdx.x;
    const int grp = bid / 13;
    const int rem = bid % 13;
    const int tid = threadIdx.x;

    if (rem >= 4) {
        // ---------------- prep_bias tile (LDS transpose -> fp16 out) ------
        float* tl = (float*)smem_raw;     // 16 x 516 f32 = 33024B
        const int pid = grp * 9 + (rem - 4);      // 0..2303
        const bool isn = pid >= 2048;
        const int id2 = isn ? pid - 2048 : pid;   // (b or h)*32 + q16
        const int q16 = id2 & 31;
        const int bh = id2 >> 5;
        const float* src = (isn ? nbias : bias) + ((size_t)bh * Qn + q16 * 16) * Kn;
        fp16_t* dst = (fp16_t*)(isn ? ntile : btile) + ((size_t)id2 << 13);
        const float L = 1.4426950408889634f;

        #pragma unroll
        for (int i = 0; i < 4; i++) {
            int u = tid + i * 512;        // 2048 f32x4 units
            int row = u >> 7;             // 0..15
            int c4 = u & 127;             // col/4
            f32x4 v = *reinterpret_cast<const f32x4*>(src + (size_t)row * Kn + c4 * 4);
            *reinterpret_cast<f32x4*>(&tl[row * 516 + c4 * 4]) = v;
        }
        __syncthreads();
        #pragma unroll
        for (int i = 0; i < 4; i++) {
            int u = tid + i * 512;        // (c, lane, t), t fastest
            int t = u & 3;
            int lane = (u >> 2) & 63;
            int c = u >> 8;
            int row = lane & 15;
            int col = c * 64 + t * 16 + ((lane >> 4) << 2);
            f32x4 v = *reinterpret_cast<const f32x4*>(&tl[row * 516 + col]);
            h16x4 hv;
            #pragma unroll
            for (int k = 0; k < 4; k++) hv[k] = (fp16_t)(v[k] * L);
            *reinterpret_cast<h16x4*>(dst + c * 1024 + lane * 16 + t * 4) = hv;
        }
        return;
    }

    // -------------------- proj (R10 form) ---------------------------------
    bf16_t* smem = (bf16_t*)smem_raw;     // A-tile (16896) / scratch (8x2560)
    bf16_t* alds = smem;
    const int id = grp * 4 + rem;         // 0..1023
    const int side = id >> 9;             // 0: q_data, 1: m_data
    const int m0 = (id & 511) * 64;
    const int lane = tid & 63;
    const int w = tid >> 6;               // wave 0..7
    const int ch = w >> 2;                // 0: q|k, 1: gate|v
    const int ncb = (w & 3) * 64;
    const int c15 = lane & 15;
    const int rgrp = lane >> 4;
    const int kof = rgrp * 8;
    const float* X = side ? mdata : qdata;
    const bf16_t* Wt = side == 0 ? (ch == 0 ? wtq : wtg) : (ch == 0 ? wtk : wtv);
    const bool vout = (side == 1) && (ch == 1);

    #pragma unroll
    for (int i = 0; i < 8; i++) {
        int u = tid + i * 512;            // 4096 f32x4 units
        int row = u >> 6;
        int c4 = u & 63;
        f32x4 a4 = *reinterpret_cast<const f32x4*>(X + (size_t)(m0 + row) * 256 + c4 * 4);
        unsigned int p0, p1;
        asm("v_cvt_pk_bf16_f32 %0, %1, %2" : "=v"(p0) : "v"(a4[0]), "v"(a4[1]));
        asm("v_cvt_pk_bf16_f32 %0, %1, %2" : "=v"(p1) : "v"(a4[2]), "v"(a4[3]));
        unsigned long long pk = ((unsigned long long)p1 << 32) | p0;
        *reinterpret_cast<unsigned long long*>(&alds[row * ALDS_STRIDE + c4 * 4]) = pk;
    }
    __syncthreads();

    const bf16_t* wbase = Wt + (size_t)(ncb >> 4) * 8 * 512 + lane * 8;
    f32x4 acc[4][4] = {};
    #pragma unroll
    for (int kc = 0; kc < 8; kc++) {
        bf16x8 am[4], bn[4];
        #pragma unroll
        for (int i = 0; i < 4; i++)
            am[i] = *reinterpret_cast<const bf16x8*>(&alds[(i * 16 + c15) * ALDS_STRIDE + kc * 32 + kof]);
        #pragma unroll
        for (int j = 0; j < 4; j++)
            bn[j] = *reinterpret_cast<const bf16x8*>(wbase + ((size_t)j * 8 + kc) * 512);
        #pragma unroll
        for (int i = 0; i < 4; i++)
            #pragma unroll
            for (int j = 0; j < 4; j++) {
                if (vout)
                    acc[i][j] = __builtin_amdgcn_mfma_f32_16x16x32_bf16(bn[j], am[i], acc[i][j], 0, 0, 0);
                else
                    acc[i][j] = __builtin_amdgcn_mfma_f32_16x16x32_bf16(am[i], bn[j], acc[i][j], 0, 0, 0);
            }
    }

    __syncthreads();                      // all alds A-tile reads done; reuse as scratch
    bf16_t* scr = smem + w * 2560;        // per-wave slice, 16B-aligned

    // q is pre-scaled by log2(e)/sqrt(32): softmax computes exp2 directly.
    const float scale = 0.17677669529663687f * 1.4426950408889634f;
    const int hbase = ncb >> 5;
    const int posbase = m0 & 511;
    const int b = m0 >> 9;

    if (!vout) {
        bf16_t* dst = side == 0 ? (ch == 0 ? qb : gateb) : kb;
        #pragma unroll
        for (int P = 0; P < 2; P++) {
            // stage 2 i-slices (32 rows x 64 cols) -> scr[row][col], stride 72
            #pragma unroll
            for (int ii = 0; ii < 2; ii++) {
                int i = P * 2 + ii;
                #pragma unroll
                for (int j = 0; j < 4; j++) {
                    int n = ncb + j * 16 + c15;
                    #pragma unroll
                    for (int r = 0; r < 4; r++) {
                        float v = acc[i][j][r];
                        if (side == 0) {
                            if (ch == 0) v *= scale;
                            else v = 1.f / (1.f + __expf(-(v + gating_b[n])));
                        }
                        scr[(ii * 16 + rgrp * 4 + r) * 72 + j * 16 + c15] = tob(v);
                    }
                }
            }
            asm volatile("" ::: "memory");
            // coalesced write-out: 4 iters x 16B/lane, full 64B lines/instr
            #pragma unroll
            for (int v2 = 0; v2 < 4; v2++) {
                int row = v2 * 8 + (lane >> 3);
                int col = (lane & 7) * 8;
                bf16x8 val = *reinterpret_cast<const bf16x8*>(&scr[row * 72 + col]);
                int pos = posbase + P * 32 + row;
                int hh = hbase + (col >> 5);
                int d = col & 31;
                *reinterpret_cast<bf16x8*>(dst + (((size_t)(b * Hn + hh) * Qn + pos) << 5) + d) = val;
            }
            asm volatile("" ::: "memory");   // pass1 writes after pass0 reads
        }
    } else {
        // transposed acc: lanes index m-rows (key positions), regs index n=(h,d)
        // kk perm folded into the LDS WRITE column; readback is stride-1 in kk.
        #pragma unroll
        for (int P = 0; P < 2; P++) {
            #pragma unroll
            for (int ii = 0; ii < 2; ii++) {
                int i = P * 2 + ii;
                int kperm = (((c15 >> 3) & 1) << 4) | (((c15 >> 2) & 1) << 3) | (ii << 2)
                          | (((c15 >> 1) & 1) << 1) | (c15 & 1);
                #pragma unroll
                for (int j = 0; j < 4; j++)
                    #pragma unroll
                    for (int r = 0; r < 4; r++)
                        scr[(j * 16 + rgrp * 4 + r) * 40 + kperm] = tob(acc[i][j][r]);
            }
            asm volatile("" ::: "memory");
            #pragma unroll
            for (int u = 0; u < 4; u++) {
                int nloc = u * 16 + (lane >> 2);
                int koff = (lane & 3) * 8;
                bf16x8 val = *reinterpret_cast<const bf16x8*>(&scr[nloc * 40 + koff]);
                int hh = hbase + (nloc >> 5);
                int d = nloc & 31;
                *reinterpret_cast<bf16x8*>(vTb + ((size_t)(b * Hn + hh) * HDn + d) * Kn
                                           + posbase + P * 32 + koff) = val;
            }
            asm volatile("" ::: "memory");
        }
    }
}

// ---------------- fused attention, FP16-TILED-BIAS (R15) ------------------
// bias/nbias pre-tiled fp16 (pre-scaled by log2e) -> per chunk, 4 coalesced
// 16B loads (was 8; bytes halved -- attn was bias-L2-BW-bound at ~35 TB/s).
// LDS = 16KB kv dbuf only. Counted vmcnt(4): at the wait, outstanding =
// stage(c)[2 oldest] + bias(c)[4 newer].
__global__ __launch_bounds__(256) void attn_kernel(
    const bf16_t* __restrict__ qb, const bf16_t* __restrict__ kb,
    const bf16_t* __restrict__ vTb, const bf16_t* __restrict__ gateb,
    const float* __restrict__ btile, const float* __restrict__ ntile,
    bf16_t* __restrict__ wab)
{
    __shared__ __align__(16) char kvlds[2][8192];    // [buf][K 4KB | V 4KB]
    const int p = blockIdx.x;
    const int qt = p & 7;
    const int h = (p >> 3) & 7;
    const int b = p >> 6;
    const int lane = threadIdx.x & 63;
    const int wv = threadIdx.x >> 6;
    const int q0 = qt * 64 + wv * 16;
    const int q16 = qt * 4 + wv;
    const int c15 = lane & 15;
    const int rgrp = lane >> 4;
    const int kof = rgrp * 8;

    const bf16_t* qbase = qb + (size_t)(b * Hn + h) * Qn * HDn;
    const bf16_t* kbase = kb + (size_t)(b * Hn + h) * Kn * HDn;
    const bf16_t* vbase = vTb + (size_t)(b * Hn + h) * HDn * Kn;
    const fp16_t* btb = (const fp16_t*)btile + (((size_t)b * 32 + q16) << 13) + lane * 16;
    const fp16_t* ntb = (const fp16_t*)ntile + (((size_t)h * 32 + q16) << 13) + lane * 16;

    // staging lane geometry (constant per thread)
    const int krw = (wv << 4) + (lane >> 2);        // K row 0..63
    const int kcb = (lane & 3) << 4;                // K col byte
    const int vrw = (wv << 3) + (lane >> 3);        // V row 0..31
    const int vcb = (lane & 7) << 4;                // V col byte
    const size_t ksrc0 = ((size_t)krw << 6) + (size_t)(kcb ^ ((krw & 3) << 4));
    const size_t vsrc0 = ((size_t)vrw << 10) + (size_t)(vcb ^ ((vrw & 7) << 4));

    bf16x8 aq = *reinterpret_cast<const bf16x8*>(qbase + (q0 + c15) * HDn + kof);

    const float NML = -12.f * 1.4426950408889634f;   // -M*log2e, folded into QK^T C
    const f32x4 zML = {NML, NML, NML, NML};
    f32x4 o[2] = {};
    f32x4 lsv = {0.f, 0.f, 0.f, 0.f};

    // ---- prologue: stage chunk 0 -> LDS buf 0 ----
    gl_lds16((const char*)kbase + ksrc0, (char*)kvlds[0] + wv * 1024);
    gl_lds16((const char*)vbase + vsrc0, (char*)kvlds[0] + 4096 + wv * 1024);

    #pragma unroll 1
    for (int c = 0; c < 8; c++) {         // 8 chunks of 64 k-cols
        const int pb = c & 1;
        // ---- bias/nbias fp16 tiled loads: 4 coalesced 16B (newest VMEM) ----
        h16x8 bt0 = *reinterpret_cast<const h16x8*>(btb + c * 1024);
        h16x8 bt1 = *reinterpret_cast<const h16x8*>(btb + c * 1024 + 8);
        h16x8 nt0 = *reinterpret_cast<const h16x8*>(ntb + c * 1024);
        h16x8 nt1 = *reinterpret_cast<const h16x8*>(ntb + c * 1024 + 8);
        // ---- counted drain: kill stage(c) [2 oldest], keep bias [4] ----
        __builtin_amdgcn_sched_barrier(0);
        asm volatile("s_waitcnt vmcnt(4)" ::: "memory");
        __builtin_amdgcn_s_barrier();
        __builtin_amdgcn_sched_barrier(0);
        // ---- issue stage(c+1) into the other buffer (safe: post-barrier) --
        if (c < 7) {
            char* dstb = (char*)kvlds[pb ^ 1] + wv * 1024;
            gl_lds16((const char*)kbase + (size_t)((c + 1) << 12) + ksrc0, dstb);
            gl_lds16((const char*)vbase + (size_t)((c + 1) << 7) + vsrc0, dstb + 4096);
        }
        // ---- QK^T from LDS K tile (swizzled read) ----
        const char* kl = (const char*)kvlds[pb];
        f32x4 sc[4];
        #pragma unroll
        for (int t = 0; t < 4; t++) {
            int kr = t * 16 + c15;
            bf16x8 kf = *reinterpret_cast<const bf16x8*>(kl + (kr << 6) + ((rgrp << 4) ^ ((kr & 3) << 4)));
            sc[t] = __builtin_amdgcn_mfma_f32_16x16x32_bf16(kf, aq, zML, 0, 0, 0);
        }
        // ---- softmax: e = exp2(sc + bb); bb from fp16 tiles; cvt_pk P ----
        f32x4 es[4];
        #pragma unroll
        for (int t = 0; t < 4; t++) {
            #pragma unroll
            for (int r = 0; r < 4; r++) {
                int j = (t & 1) * 4 + r;
                float bbv = (t < 2)
                    ? ((float)bt0[j] + (float)nt0[j])
                    : ((float)bt1[j] + (float)nt1[j]);
                es[t][r] = __builtin_amdgcn_exp2f(sc[t][r] + bbv);
            }
            lsv += es[t];
        }
        unsigned int pw[8];
        #pragma unroll
        for (int t = 0; t < 4; t++) {
            asm("v_cvt_pk_bf16_f32 %0, %1, %2" : "=v"(pw[t * 2 + 0]) : "v"(es[t][0]), "v"(es[t][1]));
            asm("v_cvt_pk_bf16_f32 %0, %1, %2" : "=v"(pw[t * 2 + 1]) : "v"(es[t][2]), "v"(es[t][3]));
        }
        u32x4 a0 = {pw[0], pw[1], pw[2], pw[3]};
        u32x4 a1 = {pw[4], pw[5], pw[6], pw[7]};
        bf16x8 pa0 = __builtin_bit_cast(bf16x8, a0);
        bf16x8 pa1 = __builtin_bit_cast(bf16x8, a1);
        // ---- PV from LDS V tile (swizzled read), P in-register ----
        #pragma unroll
        for (int sub = 0; sub < 2; sub++) {
            bf16x8 ap = sub == 0 ? pa0 : pa1;
            #pragma unroll
            for (int nt = 0; nt < 2; nt++) {
                int vr = nt * 16 + c15;
                bf16x8 bv = *reinterpret_cast<const bf16x8*>(kl + 4096 + (vr << 7)
                                + (((sub << 6) | (rgrp << 4)) ^ ((vr & 7) << 4)));
                o[nt] = __builtin_amdgcn_mfma_f32_16x16x32_bf16(ap, bv, o[nt], 0, 0, 0);
            }
        }
    }

    float lsum = (lsv[0] + lsv[1]) + (lsv[2] + lsv[3]);
    lsum += __shfl_xor(lsum, 16, 64);
    lsum += __shfl_xor(lsum, 32, 64);
    float linv[4];
    #pragma unroll
    for (int r = 0; r < 4; r++)
        linv[r] = 1.f / __shfl(lsum, rgrp * 4 + r, 64);

    // epilogue: normalize, gate, store wa as bf16 [B,Q,H*HD]
    const bf16_t* gptr = gateb + (size_t)(b * Hn + h) * Qn * HDn;
    bf16_t* wptr = wab + (size_t)b * Qn * 256;
    const int qg = q0 + rgrp * 4;
    #pragma unroll
    for (int nt = 0; nt < 2; nt++) {
        int d = nt * 16 + c15;
        #pragma unroll
        for (int r = 0; r < 4; r++) {
            float g = (float)gptr[(qg + r) * HDn + d];
            wptr[(qg + r) * 256 + h * 32 + d] = tob(o[nt][r] * linv[r] * g);
        }
    }
}

// ---------------- output projection + bias ----------------
__global__ __launch_bounds__(256) void outproj_kernel(
    const bf16_t* __restrict__ wab, const bf16_t* __restrict__ wto,
    const float* __restrict__ outb, float* __restrict__ out)
{
    __shared__ bf16_t alds[64 * ALDS_STRIDE];
    const int m0 = blockIdx.x * 64;
    const int tid = threadIdx.x;
    const int lane = tid & 63;
    const int w = tid >> 6;
    const int ncb = w * 64;
    const int c15 = lane & 15;
    const int rgrp = lane >> 4;
    const int kof = rgrp * 8;

    #pragma unroll
    for (int i = 0; i < 8; i++) {
        int u = tid + i * 256;
        int row = u >> 5;
        int c16 = u & 31;
        bf16x8 a8 = *reinterpret_cast<const bf16x8*>(wab + (size_t)(m0 + row) * 256 + c16 * 8);
        *reinterpret_cast<bf16x8*>(&alds[row * ALDS_STRIDE + c16 * 8]) = a8;
    }
    __syncthreads();

    const bf16_t* wbase = wto + (size_t)(ncb >> 4) * 8 * 512 + lane * 8;
    f32x4 acc[4][4] = {};
    #pragma unroll
    for (int kc = 0; kc < 8; kc++) {
        bf16x8 am[4], bn[4];
        #pragma unroll
        for (int i = 0; i < 4; i++)
            am[i] = *reinterpret_cast<const bf16x8*>(&alds[(i * 16 + c15) * ALDS_STRIDE + kc * 32 + kof]);
        #pragma unroll
        for (int j = 0; j < 4; j++)
            bn[j] = *reinterpret_cast<const bf16x8*>(wbase + ((size_t)j * 8 + kc) * 512);
        #pragma unroll
        for (int i = 0; i < 4; i++)
            #pragma unroll
            for (int j = 0; j < 4; j++)
                acc[i][j] = __builtin_amdgcn_mfma_f32_16x16x32_bf16(am[i], bn[j], acc[i][j], 0, 0, 0);
    }

    #pragma unroll
    for (int j = 0; j < 4; j++) {
        int n = ncb + j * 16 + c15;
        float ob = outb[n];
        #pragma unroll
        for (int i = 0; i < 4; i++) {
            #pragma unroll
            for (int r = 0; r < 4; r++) {
                int m = m0 + i * 16 + rgrp * 4 + r;
                out[(size_t)m * 256 + n] = acc[i][j][r] + ob;
            }
        }
    }
}

extern "C" void kernel_launch(void* const* d_in, const int* in_sizes, int n_in,
                              void* d_out, int out_size, void* d_ws, size_t ws_size,
                              hipStream_t stream) {
    const float* q_data = (const float*)d_in[0];
    const float* m_data = (const float*)d_in[1];
    const float* bias = (const float*)d_in[2];
    const float* nbias = (const float*)d_in[3];
    const float* query_w = (const float*)d_in[4];
    const float* key_w = (const float*)d_in[5];
    const float* value_w = (const float*)d_in[6];
    const float* gating_w = (const float*)d_in[7];
    const float* gating_b = (const float*)d_in[8];
    const float* output_w = (const float*)d_in[9];
    const float* output_b = (const float*)d_in[10];
    float* out = (float*)d_out;

    char* ws = (char*)d_ws;
    const size_t WT = 256 * 256 * sizeof(bf16_t);
    const size_t PROJ = (size_t)Bb * Hn * Qn * HDn;      // bf16 elems
    bf16_t* wtq = (bf16_t*)(ws);
    bf16_t* wtk = (bf16_t*)(ws + WT);
    bf16_t* wtv = (bf16_t*)(ws + 2 * WT);
    bf16_t* wtg = (bf16_t*)(ws + 3 * WT);
    bf16_t* wto = (bf16_t*)(ws + 4 * WT);
    bf16_t* qb = (bf16_t*)(ws + 5 * WT);
    bf16_t* kb = qb + PROJ;
    bf16_t* vtb = kb + PROJ;
    bf16_t* gateb = vtb + PROJ;
    bf16_t* wab = gateb + PROJ;

    const size_t BASE = 5 * WT + 5 * PROJ * sizeof(bf16_t);
    const size_t BT_BYTES = (size_t)64 * 32 * 8192 * 2;  // fp16 tiles, 33.5 MB
    float* btile = (float*)(ws + BASE);
    float* ntile = (float*)(ws + BASE + BT_BYTES);

    prep_weights<<<1280, 256, 0, stream>>>(query_w, key_w, value_w, gating_w, output_w,
                                           wtq, wtk, wtv, wtg, wto);
    proj_prep_kernel<<<3328, 512, 0, stream>>>(q_data, m_data, wtq, wtk, wtv, wtg,
                                               gating_b, qb, kb, vtb, gateb,
                                               bias, nbias, btile, ntile);
    attn_kernel<<<4096, 256, 0, stream>>>(qb, kb, vtb, gateb, btile, ntile, wab);
    outproj_kernel<<<512, 256, 0, stream>>>(wab, wto, output_b, out);
}